// Round 1
// baseline (242.372 us; speedup 1.0000x reference)
//
#include <hip/hip_runtime.h>
#include <hip/hip_bf16.h>
#include <stdint.h>

#define IN_F   4096
#define OUT_F  4096
#define M_ROWS 2048
#define NG     32
#define GRP    128

typedef __bf16 bf16x8 __attribute__((ext_vector_type(8)));
typedef float  f32x4  __attribute__((ext_vector_type(4)));

typedef const void __attribute__((address_space(1))) cv_g;
typedef void       __attribute__((address_space(3))) v_l;

__device__ __forceinline__ void async16(const void* g, void* l) {
  // global -> LDS direct copy, 16B per lane; LDS dest is wave-uniform base + lane*16
  __builtin_amdgcn_global_load_lds((cv_g*)g, (v_l*)l, 16, 0, 0);
}

// perm dtype flag: 1 if the perm buffer is int64, 0 if int32.
__device__ int g_perm_is64;

__global__ void decode_flag(const void* __restrict__ perm_raw) {
  if (threadIdx.x == 0 && blockIdx.x == 0) {
    const int* w = (const int*)perm_raw;
    int ok = 1;
    for (int j = 0; j < 32; ++j) {
      int lo = w[2 * j], hi = w[2 * j + 1];
      // int64 little-endian values in [0,4096) -> hi word always 0.
      // int32 data: odd words are permutation values, essentially never all zero.
      if (hi != 0 || lo < 0 || lo >= IN_F) { ok = 0; break; }
    }
    g_perm_is64 = ok;
  }
}

// xp[m, j] = bf16( x[m, perm[j]] ), 8 consecutive j per thread, 16B store.
__global__ void gather_x(const float* __restrict__ x, const void* __restrict__ perm_raw,
                         __hip_bfloat16* __restrict__ xp) {
  int t  = blockIdx.x * blockDim.x + threadIdx.x;  // 0 .. 2048*512-1
  int m  = t >> 9;
  int jb = (t & 511) << 3;
  const int f = g_perm_is64;
  const long long* p64 = (const long long*)perm_raw;
  const int*       p32 = (const int*)perm_raw;
  const float* xr = x + (size_t)m * IN_F;
  __hip_bfloat16 tmp[8] __attribute__((aligned(16)));
#pragma unroll
  for (int u = 0; u < 8; ++u) {
    int pj = f ? (int)p64[jb + u] : p32[jb + u];
    tmp[u] = __float2bfloat16(xr[pj]);
  }
  *(uint4*)(xp + (size_t)m * IN_F + jb) = *(const uint4*)tmp;
}

// wf[o, k] = bf16( w_q[o,k] * s_w[k/128, o] )  -- group scale folded into weight.
__global__ void conv_w(const int* __restrict__ w_q, const float* __restrict__ s_w,
                       __hip_bfloat16* __restrict__ wf) {
  int t  = blockIdx.x * blockDim.x + threadIdx.x;  // 0 .. 4096*1024-1
  int o  = t >> 10;
  int kb = (t & 1023) << 2;                         // 4 consecutive k, same group (4|128)
  float s = s_w[(size_t)(kb >> 7) * OUT_F + o];
  int4 w = *(const int4*)(w_q + (size_t)o * IN_F + kb);
  __hip_bfloat16 tmp[4] __attribute__((aligned(8)));
  tmp[0] = __float2bfloat16((float)w.x * s);
  tmp[1] = __float2bfloat16((float)w.y * s);
  tmp[2] = __float2bfloat16((float)w.z * s);
  tmp[3] = __float2bfloat16((float)w.w * s);
  *(uint2*)(wf + (size_t)o * IN_F + kb) = *(const uint2*)tmp;
}

// C[m,o] = sum_k A[m,k]*B[o,k] + bias[o]; A: M x K bf16, B: N x K bf16 (pre-transposed).
// 128x128 block tile, BK=32, 256 threads = 4 waves (2x2), each wave 64x64 via 4x4 MFMA 16x16x32.
__global__ __launch_bounds__(256) void gemm_bt(
    const __hip_bfloat16* __restrict__ A,
    const __hip_bfloat16* __restrict__ B,
    const float* __restrict__ bias,
    float* __restrict__ C) {
  __shared__ __hip_bfloat16 sA[128 * 32];  // row-major 128 x 32, no padding (global_load_lds constraint)
  __shared__ __hip_bfloat16 sB[128 * 32];

  const int tid  = threadIdx.x;
  const int wave = tid >> 6;
  const int lane = tid & 63;
  const int bm = blockIdx.y << 7;
  const int bn = blockIdx.x << 7;
  const int wm = (wave >> 1) << 6;   // wave row offset in tile
  const int wn = (wave & 1) << 6;    // wave col offset in tile
  const int lrow = lane & 15;
  const int quad = lane >> 4;

  f32x4 acc[4][4] = {};

  // Staging: 16B chunk id c = wave*64 + lane (+256 for second half);
  // row = c>>2, colchunk = c&3; LDS byte addr = c*16 (contiguous, lane-ordered).
  const int srow = (wave << 4) + (lane >> 2);  // 0..63
  const int sq   = lane & 3;
  const __hip_bfloat16* gA0 = A + (size_t)(bm + srow) * IN_F + sq * 8;
  const __hip_bfloat16* gA1 = gA0 + (size_t)64 * IN_F;
  const __hip_bfloat16* gB0 = B + (size_t)(bn + srow) * IN_F + sq * 8;
  const __hip_bfloat16* gB1 = gB0 + (size_t)64 * IN_F;
  __hip_bfloat16* lA0 = &sA[wave * 512];        // wave-uniform LDS bases
  __hip_bfloat16* lA1 = lA0 + 2048;             // +4096 bytes
  __hip_bfloat16* lB0 = &sB[wave * 512];
  __hip_bfloat16* lB1 = lB0 + 2048;

  for (int k0 = 0; k0 < IN_F; k0 += 32) {
    async16(gA0 + k0, lA0);
    async16(gA1 + k0, lA1);
    async16(gB0 + k0, lB0);
    async16(gB1 + k0, lB1);
    __syncthreads();  // drains vmcnt -> staged data visible

    bf16x8 af[4], bf[4];
#pragma unroll
    for (int i = 0; i < 4; ++i)
      af[i] = *(const bf16x8*)&sA[(wm + i * 16 + lrow) * 32 + quad * 8];
#pragma unroll
    for (int j = 0; j < 4; ++j)
      bf[j] = *(const bf16x8*)&sB[(wn + j * 16 + lrow) * 32 + quad * 8];

#pragma unroll
    for (int i = 0; i < 4; ++i)
#pragma unroll
      for (int j = 0; j < 4; ++j)
        acc[i][j] = __builtin_amdgcn_mfma_f32_16x16x32_bf16(af[i], bf[j], acc[i][j], 0, 0, 0);

    __syncthreads();  // protect LDS from next iteration's staging
  }

  // Epilogue: C/D layout col=lane&15, row=quad*4+reg  [measured m89/m91]
#pragma unroll
  for (int i = 0; i < 4; ++i) {
    int row = bm + wm + i * 16 + quad * 4;
#pragma unroll
    for (int j = 0; j < 4; ++j) {
      int col = bn + wn + j * 16 + lrow;
      float bv = bias[col];
#pragma unroll
      for (int r = 0; r < 4; ++r)
        C[(size_t)(row + r) * OUT_F + col] = acc[i][j][r] + bv;
    }
  }
}

// Correct-but-slow fp32 fallback if workspace is too small for bf16 staging.
__global__ void naive_fallback(const float* __restrict__ x, const int* __restrict__ w_q,
                               const float* __restrict__ s_w, const void* __restrict__ perm_raw,
                               const float* __restrict__ bias, float* __restrict__ out) {
  int t = blockIdx.x * blockDim.x + threadIdx.x;  // 0 .. 2048*4096-1
  int m = t >> 12;
  int o = t & 4095;
  const int f = g_perm_is64;
  const long long* p64 = (const long long*)perm_raw;
  const int*       p32 = (const int*)perm_raw;
  const float* xr = x + (size_t)m * IN_F;
  const int*   wr = w_q + (size_t)o * IN_F;
  float acc = 0.f;
  for (int g = 0; g < NG; ++g) {
    float part = 0.f;
    for (int k = 0; k < GRP; ++k) {
      int j = g * GRP + k;
      int pj = f ? (int)p64[j] : p32[j];
      part += xr[pj] * (float)wr[j];
    }
    acc += part * s_w[(size_t)g * OUT_F + o];
  }
  out[t] = acc + bias[o];
}

extern "C" void kernel_launch(void* const* d_in, const int* in_sizes, int n_in,
                              void* d_out, int out_size, void* d_ws, size_t ws_size,
                              hipStream_t stream) {
  const float* x    = (const float*)d_in[0];
  const int*   w_q  = (const int*)d_in[1];
  const float* s_w  = (const float*)d_in[2];
  const void*  perm = d_in[3];   // int64 or int32 -- detected on device
  const float* bias = (const float*)d_in[4];
  float* out = (float*)d_out;

  const size_t xp_bytes = (size_t)M_ROWS * IN_F * sizeof(__hip_bfloat16);  // 16 MiB
  const size_t wf_bytes = (size_t)OUT_F * IN_F * sizeof(__hip_bfloat16);   // 32 MiB
  const size_t need = xp_bytes + wf_bytes;

  decode_flag<<<1, 64, 0, stream>>>(perm);

  if (ws_size < need) {
    naive_fallback<<<(M_ROWS * OUT_F) / 256, 256, 0, stream>>>(x, w_q, s_w, perm, bias, out);
    return;
  }

  __hip_bfloat16* xp = (__hip_bfloat16*)d_ws;
  __hip_bfloat16* wf = (__hip_bfloat16*)((char*)d_ws + xp_bytes);

  gather_x<<<(M_ROWS * IN_F / 8) / 256, 256, 0, stream>>>(x, perm, xp);
  conv_w<<<(OUT_F * IN_F / 4) / 256, 256, 0, stream>>>(w_q, s_w, wf);

  dim3 grid(OUT_F / 128, M_ROWS / 128);  // 32 x 16 = 512 blocks
  gemm_bt<<<grid, 256, 0, stream>>>(xp, wf, bias, out);
}